// Round 8
// baseline (787.395 us; speedup 1.0000x reference)
//
#include <hip/hip_runtime.h>

// 12-bit ripple-carry adder over {0,1}-valued float32.
// Semantics == integer add: pack 12 bits (index 11 = LSB), add, unpack 13 bits.
// Inputs are exactly 0.0f / 1.0f; bit 29 of the f32 pattern distinguishes them.
//
// R4 (direct, 48B-stride) = 165us; R6 (LDS-staged, fully coalesced) = 160us.
// Coalescing was NOT the limiter. This round: falsify "MLP-limited" vs
// "environment BW ceiling (~3.9 TB/s logical)". 2 rows/thread = 12 uint4
// loads in flight, no LDS, no barriers; nontemporal stores so the 218 MB
// output doesn't evict L3-resident input (FETCH counter will show this).
// R7 fix: __builtin_nontemporal_store needs native Clang vectors, not
// HIP_vector_type structs -> use ext_vector_type(4/2) uints.

typedef unsigned uv4 __attribute__((ext_vector_type(4)));
typedef unsigned uv2 __attribute__((ext_vector_type(2)));

#define BATCHN  4194304u
#define NBLOCKS 2048u
#define NTH     (NBLOCKS * 256u)        // 524288 threads
#define ITERS   (BATCHN / (NTH * 2u))   // 4 iterations x 2 rows/thread

__global__ __launch_bounds__(256) void adder12_kernel(
    const uv4* __restrict__ A4,         // uv4 view of [BATCH][12] f32
    const uv4* __restrict__ B4,
    uv4* __restrict__ S4,               // uv4 view of sums
    uv2* __restrict__ C2)               // carry, 2 rows per thread -> uv2
{
    const unsigned ONE = 0x3F800000u;   // 1.0f
    const unsigned gid = blockIdx.x * 256u + threadIdx.x;

    #pragma unroll
    for (unsigned it = 0; it < ITERS; ++it) {
        const size_t row0 = 2u * ((size_t)it * NTH + gid);  // 2 consecutive rows
        const size_t p = row0 * 3;                          // uv4 index

        // 12 independent 16B loads issued back-to-back (96B/row x 2 rows)
        uv4 ra0 = A4[p+0], ra1 = A4[p+1], ra2 = A4[p+2];
        uv4 ra3 = A4[p+3], ra4 = A4[p+4], ra5 = A4[p+5];
        uv4 rb0 = B4[p+0], rb1 = B4[p+1], rb2 = B4[p+2];
        uv4 rb3 = B4[p+3], rb4 = B4[p+4], rb5 = B4[p+5];

        // pack one row: output bit j lives at integer bit (11-j); bit 29 of
        // the f32 pattern distinguishes 1.0f (0x3F800000) from 0.0f
        auto pack = [](uv4 v0, uv4 v1, uv4 v2) -> unsigned {
            unsigned u[12] = {v0.x, v0.y, v0.z, v0.w,
                              v1.x, v1.y, v1.z, v1.w,
                              v2.x, v2.y, v2.z, v2.w};
            unsigned r = 0u;
            #pragma unroll
            for (int j = 0; j < 12; ++j)
                r |= ((u[j] >> 29) & 1u) << (11 - j);
            return r;
        };

        const unsigned s0 = pack(ra0, ra1, ra2) + pack(rb0, rb1, rb2);
        const unsigned s1 = pack(ra3, ra4, ra5) + pack(rb3, rb4, rb5);

        auto unp = [ONE](unsigned s, int j) -> unsigned {
            return ((s >> (11 - j)) & 1u) ? ONE : 0u;
        };

        uv4 o0 = {unp(s0,0), unp(s0,1), unp(s0,2),  unp(s0,3)};
        uv4 o1 = {unp(s0,4), unp(s0,5), unp(s0,6),  unp(s0,7)};
        uv4 o2 = {unp(s0,8), unp(s0,9), unp(s0,10), unp(s0,11)};
        uv4 o3 = {unp(s1,0), unp(s1,1), unp(s1,2),  unp(s1,3)};
        uv4 o4 = {unp(s1,4), unp(s1,5), unp(s1,6),  unp(s1,7)};
        uv4 o5 = {unp(s1,8), unp(s1,9), unp(s1,10), unp(s1,11)};

        __builtin_nontemporal_store(o0, &S4[p+0]);
        __builtin_nontemporal_store(o1, &S4[p+1]);
        __builtin_nontemporal_store(o2, &S4[p+2]);
        __builtin_nontemporal_store(o3, &S4[p+3]);
        __builtin_nontemporal_store(o4, &S4[p+4]);
        __builtin_nontemporal_store(o5, &S4[p+5]);

        uv2 cv = {((s0 >> 12) & 1u) ? ONE : 0u,
                  ((s1 >> 12) & 1u) ? ONE : 0u};
        __builtin_nontemporal_store(cv, &C2[(size_t)it * NTH + gid]);
    }
}

extern "C" void kernel_launch(void* const* d_in, const int* in_sizes, int n_in,
                              void* d_out, int out_size, void* d_ws, size_t ws_size,
                              hipStream_t stream) {
    const uv4* A = (const uv4*)d_in[0];
    const uv4* B = (const uv4*)d_in[1];
    uv4* sums = (uv4*)d_out;                                  // BATCH*12 f32
    uv2* c2   = (uv2*)((float*)d_out + (size_t)BATCHN * 12);

    dim3 grid(NBLOCKS), block(256);
    adder12_kernel<<<grid, block, 0, stream>>>(A, B, sums, c2);
}

// Round 9
// 515.682 us; speedup vs baseline: 1.5269x; 1.5269x over previous
//
#include <hip/hip_runtime.h>

// 12-bit ripple-carry adder over {0,1}-valued float32.
// Semantics == integer add: pack 12 bits (index 11 = LSB), add, unpack 13 bits.
// Inputs are exactly 0.0f / 1.0f; bit 29 of the f32 pattern distinguishes them.
//
// History: R4 direct(48B-stride)=165us; R6 LDS-coalesced=160us; R8 = this
// structure + nontemporal stores = 492us with WRITE_SIZE 2.44x ideal.
// nt + partial-line-per-instruction stores bypass L2 write-merging -> DRAM
// write amplification. THIS ROUND: R8 minus nt (single change). Clean test of
// "more MLP (12 loads in flight, no LDS/barriers)" vs "~3.9 TB/s box ceiling".

typedef unsigned uv4 __attribute__((ext_vector_type(4)));
typedef unsigned uv2 __attribute__((ext_vector_type(2)));

#define BATCHN  4194304u
#define NBLOCKS 2048u
#define NTH     (NBLOCKS * 256u)        // 524288 threads
#define ITERS   (BATCHN / (NTH * 2u))   // 4 iterations x 2 rows/thread

__global__ __launch_bounds__(256) void adder12_kernel(
    const uv4* __restrict__ A4,         // uv4 view of [BATCH][12] f32
    const uv4* __restrict__ B4,
    uv4* __restrict__ S4,               // uv4 view of sums
    uv2* __restrict__ C2)               // carry, 2 rows per thread -> uv2
{
    const unsigned ONE = 0x3F800000u;   // 1.0f
    const unsigned gid = blockIdx.x * 256u + threadIdx.x;

    #pragma unroll
    for (unsigned it = 0; it < ITERS; ++it) {
        const size_t row0 = 2u * ((size_t)it * NTH + gid);  // 2 consecutive rows
        const size_t p = row0 * 3;                          // uv4 index

        // 12 independent 16B loads issued back-to-back (96B/row x 2 rows)
        uv4 ra0 = A4[p+0], ra1 = A4[p+1], ra2 = A4[p+2];
        uv4 ra3 = A4[p+3], ra4 = A4[p+4], ra5 = A4[p+5];
        uv4 rb0 = B4[p+0], rb1 = B4[p+1], rb2 = B4[p+2];
        uv4 rb3 = B4[p+3], rb4 = B4[p+4], rb5 = B4[p+5];

        // pack one row: output bit j lives at integer bit (11-j); bit 29 of
        // the f32 pattern distinguishes 1.0f (0x3F800000) from 0.0f
        auto pack = [](uv4 v0, uv4 v1, uv4 v2) -> unsigned {
            unsigned u[12] = {v0.x, v0.y, v0.z, v0.w,
                              v1.x, v1.y, v1.z, v1.w,
                              v2.x, v2.y, v2.z, v2.w};
            unsigned r = 0u;
            #pragma unroll
            for (int j = 0; j < 12; ++j)
                r |= ((u[j] >> 29) & 1u) << (11 - j);
            return r;
        };

        const unsigned s0 = pack(ra0, ra1, ra2) + pack(rb0, rb1, rb2);
        const unsigned s1 = pack(ra3, ra4, ra5) + pack(rb3, rb4, rb5);

        auto unp = [ONE](unsigned s, int j) -> unsigned {
            return ((s >> (11 - j)) & 1u) ? ONE : 0u;
        };

        // normal stores: L2 merges the 48B-granular pattern into full lines
        S4[p+0] = uv4{unp(s0,0), unp(s0,1), unp(s0,2),  unp(s0,3)};
        S4[p+1] = uv4{unp(s0,4), unp(s0,5), unp(s0,6),  unp(s0,7)};
        S4[p+2] = uv4{unp(s0,8), unp(s0,9), unp(s0,10), unp(s0,11)};
        S4[p+3] = uv4{unp(s1,0), unp(s1,1), unp(s1,2),  unp(s1,3)};
        S4[p+4] = uv4{unp(s1,4), unp(s1,5), unp(s1,6),  unp(s1,7)};
        S4[p+5] = uv4{unp(s1,8), unp(s1,9), unp(s1,10), unp(s1,11)};

        C2[(size_t)it * NTH + gid] = uv2{((s0 >> 12) & 1u) ? ONE : 0u,
                                         ((s1 >> 12) & 1u) ? ONE : 0u};
    }
}

extern "C" void kernel_launch(void* const* d_in, const int* in_sizes, int n_in,
                              void* d_out, int out_size, void* d_ws, size_t ws_size,
                              hipStream_t stream) {
    const uv4* A = (const uv4*)d_in[0];
    const uv4* B = (const uv4*)d_in[1];
    uv4* sums = (uv4*)d_out;                                  // BATCH*12 f32
    uv2* c2   = (uv2*)((float*)d_out + (size_t)BATCHN * 12);

    dim3 grid(NBLOCKS), block(256);
    adder12_kernel<<<grid, block, 0, stream>>>(A, B, sums, c2);
}